// Round 1
// baseline (590.365 us; speedup 1.0000x reference)
//
#include <hip/hip_runtime.h>
#include <hip/hip_bf16.h>

// MHA forward: x[4,2048,1024] -> qkv GEMM -> flash attention -> out proj.
// All matmuls in bf16 MFMA (16x16x32), fp32 accumulate. Tolerance is bf16-floor
// (absmax/32 ~ 9.3e-3), bf16 path lands ~1e-3.

typedef __attribute__((ext_vector_type(8))) short short8;
typedef __attribute__((ext_vector_type(4))) float f32x4;

#define GLD16(g, l)                                                            \
  __builtin_amdgcn_global_load_lds(                                            \
      (const __attribute__((address_space(1))) unsigned int*)(g),              \
      (__attribute__((address_space(3))) unsigned int*)(l), 16, 0, 0)

__device__ __forceinline__ unsigned short f2b(float f) {
  union { float f; unsigned int u; } v; v.f = f;
  unsigned int u = v.u;
  return (unsigned short)((u + 0x7fffu + ((u >> 16) & 1u)) >> 16);
}

// ---------------- elementwise fp32 -> bf16 ----------------
__global__ void cvt_bf16(const float* __restrict__ in, ushort* __restrict__ out, int n) {
  int i = (blockIdx.x * blockDim.x + threadIdx.x) * 4;
  if (i + 3 < n) {
    float4 f = *(const float4*)(in + i);
    ushort4 o;
    o.x = f2b(f.x); o.y = f2b(f.y); o.z = f2b(f.z); o.w = f2b(f.w);
    *(ushort4*)(out + i) = o;
  }
}

// -------- W[K][N] fp32 -> Wt[N][K] bf16 (64x64 LDS tile transpose) --------
__global__ void transpose_cvt(const float* __restrict__ W, ushort* __restrict__ Wt,
                              int K, int N) {
  __shared__ float tile[64][65];
  int n0 = blockIdx.x * 64, k0 = blockIdx.y * 64;
  int tx = threadIdx.x & 63, ty = threadIdx.x >> 6;  // ty 0..3
#pragma unroll
  for (int i = 0; i < 64; i += 4)
    tile[ty + i][tx] = W[(size_t)(k0 + ty + i) * N + n0 + tx];
  __syncthreads();
#pragma unroll
  for (int i = 0; i < 64; i += 4)
    Wt[(size_t)(n0 + ty + i) * K + k0 + tx] = f2b(tile[tx][ty + i]);
}

// ---------------- GEMM: C[M,N] = A[M,K] @ Bt[N,K]^T + bias ----------------
// A, Bt bf16 row-major. 128x128 tile, BK=64, global_load_lds staging,
// 4 waves in 2x2 grid, each wave 64x64 = 4x4 MFMA tiles.
template <int OUTF32>
__global__ __launch_bounds__(256, 2) void gemm_bt_bias(
    const ushort* __restrict__ A, const ushort* __restrict__ Bt,
    const float* __restrict__ bias, void* __restrict__ Cout,
    int M, int N, int K) {
  __shared__ ushort As[128 * 64];
  __shared__ ushort Bs[128 * 64];
  const int lane = threadIdx.x & 63;
  const int wv = threadIdx.x >> 6;
  const int bm = blockIdx.y, bn = blockIdx.x;
  const int wm = wv >> 1, wn = wv & 1;
  f32x4 acc[4][4] = {};
  const size_t arow0 = (size_t)bm * 128;
  const size_t brow0 = (size_t)bn * 128;

  for (int k0 = 0; k0 < K; k0 += 64) {
    __syncthreads();
#pragma unroll
    for (int i = 0; i < 4; ++i) {
      int r = wv * 32 + i * 8 + (lane >> 3);
      const ushort* ga = A + (arow0 + r) * K + k0 + (lane & 7) * 8;
      GLD16(ga, As + (wv * 32 + i * 8) * 64);
      const ushort* gb = Bt + (brow0 + r) * K + k0 + (lane & 7) * 8;
      GLD16(gb, Bs + (wv * 32 + i * 8) * 64);
    }
    __syncthreads();
    short8 af[2][4], bf[2][4];
#pragma unroll
    for (int kf = 0; kf < 2; ++kf)
#pragma unroll
      for (int t = 0; t < 4; ++t) {
        af[kf][t] = *(const short8*)(As + (wm * 64 + t * 16 + (lane & 15)) * 64 +
                                     kf * 32 + (lane >> 4) * 8);
        bf[kf][t] = *(const short8*)(Bs + (wn * 64 + t * 16 + (lane & 15)) * 64 +
                                     kf * 32 + (lane >> 4) * 8);
      }
#pragma unroll
    for (int kf = 0; kf < 2; ++kf)
#pragma unroll
      for (int mt = 0; mt < 4; ++mt)
#pragma unroll
        for (int nt = 0; nt < 4; ++nt)
          acc[mt][nt] = __builtin_amdgcn_mfma_f32_16x16x32_bf16(
              af[kf][mt], bf[kf][nt], acc[mt][nt], 0, 0, 0);
  }
  // epilogue: bias + store (C layout: col=lane&15, row=(lane>>4)*4+r)
#pragma unroll
  for (int nt = 0; nt < 4; ++nt) {
    int col = bn * 128 + wn * 64 + nt * 16 + (lane & 15);
    float bv = bias[col];
#pragma unroll
    for (int mt = 0; mt < 4; ++mt) {
      int row0 = bm * 128 + wm * 64 + mt * 16 + (lane >> 4) * 4;
#pragma unroll
      for (int r = 0; r < 4; ++r) {
        float v = acc[mt][nt][r] + bv;
        if (OUTF32)
          ((float*)Cout)[(size_t)(row0 + r) * N + col] = v;
        else
          ((ushort*)Cout)[(size_t)(row0 + r) * N + col] = f2b(v);
      }
    }
  }
}

// ---------------- flash attention ----------------
// qkv bf16 [8192, 3072]; head h: q cols [192h,192h+64), k +64, v +128.
// Block = (b,h,qtile of 128 rows); 4 waves x 32 rows; KV tiles of 128.
#define L2E 1.44269504088896340736f

__global__ __launch_bounds__(256, 2) void flash_attn(
    const ushort* __restrict__ qkv, const float* __restrict__ mask,
    float* __restrict__ values_f, ushort* __restrict__ values_b) {
  // QsPs: Q tile [128][64] early, then P tiles (4 waves x 16 rows x 136) later.
  __shared__ ushort QsPs[8704];
  __shared__ ushort Ks[128 * 64];
  __shared__ ushort Vt[64 * 136];  // V transposed: [d][key], stride 136 shorts

  const int lane = threadIdx.x & 63;
  const int wv = threadIdx.x >> 6;
  const int bh = blockIdx.x >> 4;
  const int qt = blockIdx.x & 15;
  const int b = bh >> 4, h = bh & 15;
  const size_t rowbase = (size_t)b * 2048;
  const int qcol = h * 192;

  // stage Q -> QsPs
#pragma unroll
  for (int i = 0; i < 4; ++i) {
    int r = wv * 32 + i * 8 + (lane >> 3);
    const ushort* g = qkv + (rowbase + qt * 128 + r) * 3072 + qcol + (lane & 7) * 8;
    GLD16(g, QsPs + (wv * 32 + i * 8) * 64);
  }
  __syncthreads();
  short8 qf[2][2];
#pragma unroll
  for (int mt = 0; mt < 2; ++mt)
#pragma unroll
    for (int kf = 0; kf < 2; ++kf)
      qf[mt][kf] = *(const short8*)(QsPs + (wv * 32 + mt * 16 + (lane & 15)) * 64 +
                                    kf * 32 + (lane >> 4) * 8);

  f32x4 acc[2][4] = {};
  float mst[2][4], lst[2][4];
#pragma unroll
  for (int mt = 0; mt < 2; ++mt)
#pragma unroll
    for (int r = 0; r < 4; ++r) { mst[mt][r] = -1e30f; lst[mt][r] = 0.f; }

  const int tkey = threadIdx.x >> 1;        // V transpose: key row 0..127
  const int tdh = (threadIdx.x & 1) * 32;   // d half

  for (int kt = 0; kt < 16; ++kt) {
    __syncthreads();  // prev-iter Ks/Vt reads done (kt=0: qf reads drained here)
    // stage K
#pragma unroll
    for (int i = 0; i < 4; ++i) {
      int r = wv * 32 + i * 8 + (lane >> 3);
      const ushort* g =
          qkv + (rowbase + kt * 128 + r) * 3072 + qcol + 64 + (lane & 7) * 8;
      GLD16(g, Ks + (wv * 32 + i * 8) * 64);
    }
    // stage V transposed
    {
      const ushort* g =
          qkv + (rowbase + kt * 128 + tkey) * 3072 + qcol + 128 + tdh;
#pragma unroll
      for (int i = 0; i < 4; ++i) {
        short8 v8 = *(const short8*)(g + i * 8);
#pragma unroll
        for (int j = 0; j < 8; ++j)
          Vt[(tdh + i * 8 + j) * 136 + tkey] = (ushort)v8[j];
      }
    }
    __syncthreads();

    ushort* Pw = QsPs + wv * 16 * 136;
#pragma unroll
    for (int mt = 0; mt < 2; ++mt) {
      // S = Q K^T  (C: row=q=(lane>>4)*4+r, col=key=lane&15 within each nt)
      f32x4 sc[8];
#pragma unroll
      for (int nt = 0; nt < 8; ++nt) {
        f32x4 s = {};
#pragma unroll
        for (int kf = 0; kf < 2; ++kf) {
          short8 kfr = *(const short8*)(Ks + (nt * 16 + (lane & 15)) * 64 +
                                        kf * 32 + (lane >> 4) * 8);
          s = __builtin_amdgcn_mfma_f32_16x16x32_bf16(qf[mt][kf], kfr, s, 0, 0, 0);
        }
        sc[nt] = s;
      }
      // scale + additive mask
      int qrow_g = qt * 128 + wv * 32 + mt * 16 + (lane >> 4) * 4;
#pragma unroll
      for (int nt = 0; nt < 8; ++nt) {
        int kcol = kt * 128 + nt * 16 + (lane & 15);
#pragma unroll
        for (int r = 0; r < 4; ++r)
          sc[nt][r] = sc[nt][r] * 0.125f + mask[(size_t)(qrow_g + r) * 2048 + kcol];
      }
      // online softmax per row; write P (bf16) to wave-local LDS tile
      float alpha[4];
#pragma unroll
      for (int r = 0; r < 4; ++r) {
        float pm = sc[0][r];
#pragma unroll
        for (int nt = 1; nt < 8; ++nt) pm = fmaxf(pm, sc[nt][r]);
#pragma unroll
        for (int off = 1; off < 16; off <<= 1) pm = fmaxf(pm, __shfl_xor(pm, off));
        float mnew = fmaxf(mst[mt][r], pm);
        alpha[r] = exp2f((mst[mt][r] - mnew) * L2E);
        mst[mt][r] = mnew;
        float rs = 0.f;
#pragma unroll
        for (int nt = 0; nt < 8; ++nt) {
          float p = exp2f((sc[nt][r] - mnew) * L2E);
          Pw[((lane >> 4) * 4 + r) * 136 + nt * 16 + (lane & 15)] = f2b(p);
          rs += p;
        }
#pragma unroll
        for (int off = 1; off < 16; off <<= 1) rs += __shfl_xor(rs, off);
        lst[mt][r] = lst[mt][r] * alpha[r] + rs;
      }
      // rescale O accumulator
#pragma unroll
      for (int dt = 0; dt < 4; ++dt)
#pragma unroll
        for (int r = 0; r < 4; ++r) acc[mt][dt][r] *= alpha[r];
      // ensure P writes visible to our own ds_reads (+ compiler ordering)
      asm volatile("s_waitcnt lgkmcnt(0)" ::: "memory");
      // O += P V   (A from Pw, B from Vt)
      short8 af[4];
#pragma unroll
      for (int kf = 0; kf < 4; ++kf)
        af[kf] = *(const short8*)(Pw + (lane & 15) * 136 + kf * 32 + (lane >> 4) * 8);
#pragma unroll
      for (int dt = 0; dt < 4; ++dt)
#pragma unroll
        for (int kf = 0; kf < 4; ++kf) {
          short8 bfr = *(const short8*)(Vt + (dt * 16 + (lane & 15)) * 136 +
                                        kf * 32 + (lane >> 4) * 8);
          acc[mt][dt] =
              __builtin_amdgcn_mfma_f32_16x16x32_bf16(af[kf], bfr, acc[mt][dt], 0, 0, 0);
        }
    }
  }
  // epilogue: values = O / l  -> fp32 to d_out[8M..], bf16 to ws
#pragma unroll
  for (int mt = 0; mt < 2; ++mt) {
    int qrow_g = qt * 128 + wv * 32 + mt * 16 + (lane >> 4) * 4;
#pragma unroll
    for (int dt = 0; dt < 4; ++dt) {
      int col = h * 64 + dt * 16 + (lane & 15);
#pragma unroll
      for (int r = 0; r < 4; ++r) {
        float v = acc[mt][dt][r] / lst[mt][r];
        size_t idx = (rowbase + qrow_g + r) * 1024 + col;
        values_f[idx] = v;
        values_b[idx] = f2b(v);
      }
    }
  }
}

extern "C" void kernel_launch(void* const* d_in, const int* in_sizes, int n_in,
                              void* d_out, int out_size, void* d_ws, size_t ws_size,
                              hipStream_t stream) {
  const float* x    = (const float*)d_in[0];
  const float* mask = (const float*)d_in[1];
  const float* Wqkv = (const float*)d_in[2];
  const float* bqkv = (const float*)d_in[3];
  const float* Wo   = (const float*)d_in[4];
  const float* bo   = (const float*)d_in[5];
  float* out      = (float*)d_out;
  float* values_f = out + 8388608;

  char* ws = (char*)d_ws;
  ushort* xb    = (ushort*)(ws + 0);          // 16 MB  [8192,1024] bf16
  ushort* wqkvt = (ushort*)(ws + 16777216);   // 6 MB   [3072,1024] bf16 (W_qkv^T)
  ushort* wot   = (ushort*)(ws + 23068672);   // 2 MB   [1024,1024] bf16 (W_o^T)
  ushort* qkv   = (ushort*)(ws + 25165824);   // 48 MB  [8192,3072] bf16
  ushort* valb  = (ushort*)(ws + 75497472);   // 16 MB  [8192,1024] bf16

  cvt_bf16<<<dim3(8192), dim3(256), 0, stream>>>(x, xb, 8388608);
  transpose_cvt<<<dim3(48, 16), dim3(256), 0, stream>>>(Wqkv, wqkvt, 1024, 3072);
  transpose_cvt<<<dim3(16, 16), dim3(256), 0, stream>>>(Wo, wot, 1024, 1024);
  gemm_bt_bias<0><<<dim3(24, 64), dim3(256), 0, stream>>>(
      xb, wqkvt, bqkv, (void*)qkv, 8192, 3072, 1024);
  flash_attn<<<dim3(1024), dim3(256), 0, stream>>>(qkv, mask, values_f, valb);
  gemm_bt_bias<1><<<dim3(8, 64), dim3(256), 0, stream>>>(
      valb, wot, bo, (void*)out, 8192, 1024, 1024);
}

// Round 2
// 462.091 us; speedup vs baseline: 1.2776x; 1.2776x over previous
//
#include <hip/hip_runtime.h>
#include <hip/hip_bf16.h>

// MHA forward: x[4,2048,1024] -> qkv GEMM -> flash attention (transposed
// S^T/O^T formulation, P stays in registers) -> out proj. bf16 MFMA 16x16x32.

typedef __attribute__((ext_vector_type(8))) short short8;
typedef __attribute__((ext_vector_type(4))) float f32x4;

#define GLD16(g, l)                                                            \
  __builtin_amdgcn_global_load_lds(                                            \
      (const __attribute__((address_space(1))) unsigned int*)(g),              \
      (__attribute__((address_space(3))) unsigned int*)(l), 16, 0, 0)

__device__ __forceinline__ unsigned short f2b(float f) {
  union { float f; unsigned int u; } v; v.f = f;
  unsigned int u = v.u;
  return (unsigned short)((u + 0x7fffu + ((u >> 16) & 1u)) >> 16);
}
__device__ __forceinline__ unsigned int fbits(float f) {
  union { float f; unsigned int u; } v; v.f = f; return v.u;
}
__device__ __forceinline__ float bfloat(unsigned int u) {
  union { float f; unsigned int u; } v; v.u = u; return v.f;
}

// ---------------- elementwise fp32 -> bf16 ----------------
__global__ void cvt_bf16(const float* __restrict__ in, ushort* __restrict__ out, int n) {
  int i = (blockIdx.x * blockDim.x + threadIdx.x) * 4;
  if (i + 3 < n) {
    float4 f = *(const float4*)(in + i);
    ushort4 o;
    o.x = f2b(f.x); o.y = f2b(f.y); o.z = f2b(f.z); o.w = f2b(f.w);
    *(ushort4*)(out + i) = o;
  }
}

// -------- W[K][N] fp32 -> Wt[N][K] bf16 (64x64 LDS tile transpose) --------
__global__ void transpose_cvt(const float* __restrict__ W, ushort* __restrict__ Wt,
                              int K, int N) {
  __shared__ float tile[64][65];
  int n0 = blockIdx.x * 64, k0 = blockIdx.y * 64;
  int tx = threadIdx.x & 63, ty = threadIdx.x >> 6;  // ty 0..3
#pragma unroll
  for (int i = 0; i < 64; i += 4)
    tile[ty + i][tx] = W[(size_t)(k0 + ty + i) * N + n0 + tx];
  __syncthreads();
#pragma unroll
  for (int i = 0; i < 64; i += 4)
    Wt[(size_t)(n0 + ty + i) * K + k0 + tx] = f2b(tile[tx][ty + i]);
}

// ---------------- GEMM: C[M,N] = A[M,K] @ Bt[N,K]^T + bias ----------------
template <int OUTF32>
__global__ __launch_bounds__(256, 2) void gemm_bt_bias(
    const ushort* __restrict__ A, const ushort* __restrict__ Bt,
    const float* __restrict__ bias, void* __restrict__ Cout,
    int M, int N, int K) {
  __shared__ ushort As[128 * 64];
  __shared__ ushort Bs[128 * 64];
  const int lane = threadIdx.x & 63;
  const int wv = threadIdx.x >> 6;
  const int bm = blockIdx.y, bn = blockIdx.x;
  const int wm = wv >> 1, wn = wv & 1;
  f32x4 acc[4][4] = {};
  const size_t arow0 = (size_t)bm * 128;
  const size_t brow0 = (size_t)bn * 128;

  for (int k0 = 0; k0 < K; k0 += 64) {
    __syncthreads();
#pragma unroll
    for (int i = 0; i < 4; ++i) {
      int r = wv * 32 + i * 8 + (lane >> 3);
      const ushort* ga = A + (arow0 + r) * K + k0 + (lane & 7) * 8;
      GLD16(ga, As + (wv * 32 + i * 8) * 64);
      const ushort* gb = Bt + (brow0 + r) * K + k0 + (lane & 7) * 8;
      GLD16(gb, Bs + (wv * 32 + i * 8) * 64);
    }
    __syncthreads();
    short8 af[2][4], bf[2][4];
#pragma unroll
    for (int kf = 0; kf < 2; ++kf)
#pragma unroll
      for (int t = 0; t < 4; ++t) {
        af[kf][t] = *(const short8*)(As + (wm * 64 + t * 16 + (lane & 15)) * 64 +
                                     kf * 32 + (lane >> 4) * 8);
        bf[kf][t] = *(const short8*)(Bs + (wn * 64 + t * 16 + (lane & 15)) * 64 +
                                     kf * 32 + (lane >> 4) * 8);
      }
#pragma unroll
    for (int kf = 0; kf < 2; ++kf)
#pragma unroll
      for (int mt = 0; mt < 4; ++mt)
#pragma unroll
        for (int nt = 0; nt < 4; ++nt)
          acc[mt][nt] = __builtin_amdgcn_mfma_f32_16x16x32_bf16(
              af[kf][mt], bf[kf][nt], acc[mt][nt], 0, 0, 0);
  }
#pragma unroll
  for (int nt = 0; nt < 4; ++nt) {
    int col = bn * 128 + wn * 64 + nt * 16 + (lane & 15);
    float bv = bias[col];
#pragma unroll
    for (int mt = 0; mt < 4; ++mt) {
      int row0 = bm * 128 + wm * 64 + mt * 16 + (lane >> 4) * 4;
#pragma unroll
      for (int r = 0; r < 4; ++r) {
        float v = acc[mt][nt][r] + bv;
        if (OUTF32)
          ((float*)Cout)[(size_t)(row0 + r) * N + col] = v;
        else
          ((ushort*)Cout)[(size_t)(row0 + r) * N + col] = f2b(v);
      }
    }
  }
}

// ---------------- flash attention (transposed formulation) ----------------
// qkv bf16 [8192, 3072]; head h: q cols [192h,192h+64), k +64, v +128.
// Block = (b,h,qtile of 128 rows); wave covers 32 q (2 mt-tiles of 16).
// S^T = K.Q^T  (C-layout: col=q=lane&15, row=key) -> softmax in-lane.
// O^T = V^T.P^T (P^T in registers == B-operand layout given permuted V cols).
#define SCL2E 0.1803368801111204f  /* 0.125 * log2(e) */
#define L2E   1.44269504088896340736f

__global__ __launch_bounds__(256, 2) void flash_attn(
    const ushort* __restrict__ qkv, const float* __restrict__ mask,
    float* __restrict__ values_f, ushort* __restrict__ values_b) {
  __shared__ ushort Ks[128 * 64];   // swizzled rows
  __shared__ ushort Vt[64 * 136];   // V^T, permuted key-columns, stride 136

  const int lane = threadIdx.x & 63;
  const int wv = threadIdx.x >> 6;
  const int c = lane & 15;          // q within mt-tile
  const int g = lane >> 4;          // key quarter-group
  const int bh = blockIdx.x >> 4;
  const int qt = blockIdx.x & 15;
  const int b = bh >> 4, h = bh & 15;
  const size_t rowbase = (size_t)b * 2048;
  const int qcol = h * 192;
  const int swz = (c & 3) << 1;     // read-side chunk xor for Ks

  // Q b-frags straight from global (once per block)
  short8 qf[2][2];
#pragma unroll
  for (int mt = 0; mt < 2; ++mt)
#pragma unroll
    for (int kf = 0; kf < 2; ++kf)
      qf[mt][kf] = *(const short8*)(qkv +
          (rowbase + qt * 128 + wv * 32 + mt * 16 + c) * 3072 + qcol +
          kf * 32 + g * 8);

  f32x4 acc[2][4] = {};
  float mst[2] = {-3e38f, -3e38f}, lst[2] = {0.f, 0.f};

  // V staging mapping: thread -> key pair (K0,K0+1), d-quarter dq
  const int kp = threadIdx.x & 63, dq = threadIdx.x >> 6;
  const int K0 = kp * 2;
  const int pc0 = ((K0 >> 5) << 5) + (((K0 >> 2) & 3) << 3) +
                  (((K0 >> 4) & 1) << 2) + (K0 & 3);   // permuted column of K0
  const int vdw = pc0 >> 1;                            // dword column

  const float* mrow = mask + (size_t)(qt * 128 + wv * 32 + c) * 2048 + g * 4;

  for (int kt = 0; kt < 16; ++kt) {
    __syncthreads();
    // ---- stage K (GLD16, xor-swizzled chunks) ----
    {
      int gcol = (((lane & 7) ^ (((lane >> 3) & 3) << 1)) << 3);
#pragma unroll
      for (int i = 0; i < 4; ++i) {
        int rloc = wv * 32 + i * 8;
        const ushort* gk = qkv + (rowbase + kt * 128 + rloc + (lane >> 3)) * 3072 +
                           qcol + 64 + gcol;
        GLD16(gk, Ks + rloc * 64);
      }
    }
    // ---- stage V^T (dword-packed, permuted columns) ----
    {
      const ushort* vg = qkv + (rowbase + kt * 128 + K0) * 3072 + qcol + 128 + dq * 16;
      short8 a0 = *(const short8*)(vg);
      short8 a1 = *(const short8*)(vg + 8);
      short8 b0 = *(const short8*)(vg + 3072);
      short8 b1 = *(const short8*)(vg + 3072 + 8);
      unsigned int* Vdw = (unsigned int*)Vt;
#pragma unroll
      for (int j = 0; j < 8; ++j)
        Vdw[(dq * 16 + j) * 68 + vdw] =
            ((unsigned int)(unsigned short)b0[j] << 16) | (unsigned short)a0[j];
#pragma unroll
      for (int j = 0; j < 8; ++j)
        Vdw[(dq * 16 + 8 + j) * 68 + vdw] =
            ((unsigned int)(unsigned short)b1[j] << 16) | (unsigned short)a1[j];
    }
    __syncthreads();

    const float* mkt = mrow + kt * 128;
    // mask for mt=0 issued early (overlaps QK MFMAs)
    float4 msk0[8];
#pragma unroll
    for (int nt = 0; nt < 8; ++nt) msk0[nt] = *(const float4*)(mkt + nt * 16);

    // ---- S^T = K . Q^T ----
    f32x4 sc[2][8];
#pragma unroll
    for (int nt = 0; nt < 8; ++nt) {
      short8 k0 = *(const short8*)(Ks + (nt * 16 + c) * 64 + ((g ^ swz) << 3));
      short8 k1 = *(const short8*)(Ks + (nt * 16 + c) * 64 + (((4 + g) ^ swz) << 3));
      f32x4 z = {0.f, 0.f, 0.f, 0.f};
      sc[0][nt] = __builtin_amdgcn_mfma_f32_16x16x32_bf16(k0, qf[0][0], z, 0, 0, 0);
      sc[0][nt] = __builtin_amdgcn_mfma_f32_16x16x32_bf16(k1, qf[0][1], sc[0][nt], 0, 0, 0);
      sc[1][nt] = __builtin_amdgcn_mfma_f32_16x16x32_bf16(k0, qf[1][0], z, 0, 0, 0);
      sc[1][nt] = __builtin_amdgcn_mfma_f32_16x16x32_bf16(k1, qf[1][1], sc[1][nt], 0, 0, 0);
    }

    // ---- online softmax (in-lane keys, per-lane scalar state) ----
    __attribute__((aligned(16))) unsigned int Dw[2][16];
#pragma unroll
    for (int mt = 0; mt < 2; ++mt) {
      f32x4 t4[8];
#pragma unroll
      for (int nt = 0; nt < 8; ++nt) {
        float4 mk = (mt == 0) ? msk0[nt]
                              : *(const float4*)(mkt + 16 * 2048 + nt * 16);
#pragma unroll
        for (int r = 0; r < 4; ++r)
          t4[nt][r] = sc[mt][nt][r] * SCL2E + ((const float*)&mk)[r] * L2E;
      }
      f32x4 vm = t4[0];
#pragma unroll
      for (int nt = 1; nt < 8; ++nt)
#pragma unroll
        for (int r = 0; r < 4; ++r) vm[r] = fmaxf(vm[r], t4[nt][r]);
      float pm = fmaxf(fmaxf(vm[0], vm[1]), fmaxf(vm[2], vm[3]));
      pm = fmaxf(pm, __shfl_xor(pm, 16));
      pm = fmaxf(pm, __shfl_xor(pm, 32));
      float mnew = fmaxf(mst[mt], pm);
      float alpha = exp2f(mst[mt] - mnew);
      mst[mt] = mnew;
      f32x4 rsv = {0.f, 0.f, 0.f, 0.f};
#pragma unroll
      for (int nt = 0; nt < 8; ++nt) {
        unsigned int pu[4];
#pragma unroll
        for (int r = 0; r < 4; ++r) {
          float p = exp2f(t4[nt][r] - mnew);
          pu[r] = fbits(p) & 0xffff0000u;
          rsv[r] += bfloat(pu[r]);
        }
        Dw[mt][nt * 2 + 0] = pu[1] | (pu[0] >> 16);
        Dw[mt][nt * 2 + 1] = pu[3] | (pu[2] >> 16);
      }
      float rs = (rsv[0] + rsv[1]) + (rsv[2] + rsv[3]);
      rs += __shfl_xor(rs, 16);
      rs += __shfl_xor(rs, 32);
      lst[mt] = lst[mt] * alpha + rs;
#pragma unroll
      for (int dt = 0; dt < 4; ++dt)
#pragma unroll
        for (int r = 0; r < 4; ++r) acc[mt][dt][r] *= alpha;
    }

    // ---- O^T += V^T . P^T  (B-frags are Dw in registers) ----
    const short8* bu0 = (const short8*)Dw[0];
    const short8* bu1 = (const short8*)Dw[1];
#pragma unroll
    for (int dt = 0; dt < 4; ++dt)
#pragma unroll
      for (int kf = 0; kf < 4; ++kf) {
        short8 vf = *(const short8*)(Vt + (dt * 16 + c) * 136 + kf * 32 + g * 8);
        acc[0][dt] = __builtin_amdgcn_mfma_f32_16x16x32_bf16(vf, bu0[kf], acc[0][dt], 0, 0, 0);
        acc[1][dt] = __builtin_amdgcn_mfma_f32_16x16x32_bf16(vf, bu1[kf], acc[1][dt], 0, 0, 0);
      }
  }

  // ---- epilogue: O^T col=q (per lane), rows d = dt*16 + g*4 + r ----
#pragma unroll
  for (int mt = 0; mt < 2; ++mt) {
    float rl = 1.0f / lst[mt];
    size_t qrow = rowbase + qt * 128 + wv * 32 + mt * 16 + c;
#pragma unroll
    for (int dt = 0; dt < 4; ++dt) {
      int d0 = h * 64 + dt * 16 + g * 4;
      float4 o;
      o.x = acc[mt][dt][0] * rl; o.y = acc[mt][dt][1] * rl;
      o.z = acc[mt][dt][2] * rl; o.w = acc[mt][dt][3] * rl;
      *(float4*)(values_f + qrow * 1024 + d0) = o;
      ushort4 ob;
      ob.x = f2b(o.x); ob.y = f2b(o.y); ob.z = f2b(o.z); ob.w = f2b(o.w);
      *(ushort4*)(values_b + qrow * 1024 + d0) = ob;
    }
  }
}

extern "C" void kernel_launch(void* const* d_in, const int* in_sizes, int n_in,
                              void* d_out, int out_size, void* d_ws, size_t ws_size,
                              hipStream_t stream) {
  const float* x    = (const float*)d_in[0];
  const float* mask = (const float*)d_in[1];
  const float* Wqkv = (const float*)d_in[2];
  const float* bqkv = (const float*)d_in[3];
  const float* Wo   = (const float*)d_in[4];
  const float* bo   = (const float*)d_in[5];
  float* out      = (float*)d_out;
  float* values_f = out + 8388608;

  char* ws = (char*)d_ws;
  ushort* xb    = (ushort*)(ws + 0);          // 16 MB  [8192,1024] bf16
  ushort* wqkvt = (ushort*)(ws + 16777216);   // 6 MB   [3072,1024] bf16 (W_qkv^T)
  ushort* wot   = (ushort*)(ws + 23068672);   // 2 MB   [1024,1024] bf16 (W_o^T)
  ushort* qkv   = (ushort*)(ws + 25165824);   // 48 MB  [8192,3072] bf16
  ushort* valb  = (ushort*)(ws + 75497472);   // 16 MB  [8192,1024] bf16

  cvt_bf16<<<dim3(8192), dim3(256), 0, stream>>>(x, xb, 8388608);
  transpose_cvt<<<dim3(48, 16), dim3(256), 0, stream>>>(Wqkv, wqkvt, 1024, 3072);
  transpose_cvt<<<dim3(16, 16), dim3(256), 0, stream>>>(Wo, wot, 1024, 1024);
  gemm_bt_bias<0><<<dim3(24, 64), dim3(256), 0, stream>>>(
      xb, wqkvt, bqkv, (void*)qkv, 8192, 3072, 1024);
  flash_attn<<<dim3(1024), dim3(256), 0, stream>>>(qkv, mask, values_f, valb);
  gemm_bt_bias<1><<<dim3(8, 64), dim3(256), 0, stream>>>(
      valb, wot, bo, (void*)out, 8192, 1024, 1024);
}